// Round 5
// baseline (166.404 us; speedup 1.0000x reference)
//
#include <hip/hip_runtime.h>
#include <hip/hip_bf16.h>
#include <cstdint>

#define NPOS 512
#define NNEG 512
#define BATCH 8
#define DDIM 128
#define NLEM 32768
#define NK_STEPS 32  // 4096 sim rows / 128

typedef __attribute__((ext_vector_type(4))) float f32x4;
typedef __attribute__((ext_vector_type(16))) float f32x16;
typedef __attribute__((ext_vector_type(8))) short short8;

__device__ __forceinline__ unsigned short f2bf(float f) {
  unsigned u = __float_as_uint(f);
  u = (u + 0x7FFFu + ((u >> 16) & 1u)) >> 16;
  return (unsigned short)u;
}

__device__ __forceinline__ short8 cvt8(f32x4 a0, f32x4 a1) {
  short8 w;
  w[0] = (short)f2bf(a0[0]); w[1] = (short)f2bf(a0[1]);
  w[2] = (short)f2bf(a0[2]); w[3] = (short)f2bf(a0[3]);
  w[4] = (short)f2bf(a1[0]); w[5] = (short)f2bf(a1[1]);
  w[6] = (short)f2bf(a1[2]); w[7] = (short)f2bf(a1[3]);
  return w;
}

// ---- shared newmem row logic (one wave per row, exact f32) ----
__device__ __forceinline__ void newmem_row(int r, int lane, const float* __restrict__ X,
                                           const int* __restrict__ vis,
                                           const float* __restrict__ Mem, int start,
                                           float* __restrict__ out) {
  const int d0 = lane, d1 = lane + 64;
  float v0, v1;
  if (r < NPOS) {
    const float s0 = Mem[(size_t)r * DDIM + d0];
    const float s1 = Mem[(size_t)r * DDIM + d1];
    float a0 = 0.f, a1 = 0.f;
#pragma unroll
    for (int b = 0; b < BATCH; ++b) {
      const float w = (float)vis[b * NPOS + r];
      const float* px = X + (size_t)(b * (NPOS + NNEG) + r) * DDIM;
      a0 += w * px[d0];
      a1 += w * px[d1];
    }
    v0 = 0.5f * s0 + 0.0625f * a0;
    v1 = 0.5f * s1 + 0.0625f * a1;
  } else if (r >= start && r < start + BATCH * NNEG) {
    const int q = r - start;
    const int b = q >> 9, n = q & 511;
    const float* px = X + (size_t)(b * (NPOS + NNEG) + NPOS + n) * DDIM;
    v0 = px[d0];
    v1 = px[d1];
  } else {
    v0 = Mem[(size_t)r * DDIM + d0];
    v1 = Mem[(size_t)r * DDIM + d1];
  }
  float s = v0 * v0 + v1 * v1;
#pragma unroll
  for (int off = 32; off; off >>= 1) s += __shfl_xor(s, off, 64);
  const float inv = 1.0f / fmaxf(sqrtf(s), 1e-12f);
  out[(size_t)r * DDIM + d0] = v0 * inv;
  out[(size_t)r * DDIM + d1] = v1 * inv;
}

// ==== fused persistent kernel: B-convert + banded GEMM + newmem + y ====
// Block b owns sim column band n0 = b*128 (B converted f32->bf16 in prologue,
// resident in LDS+regs). Steps k walk row panels; all blocks write the same
// contiguous 16MB row band per step. A panels staged from f32 x with
// in-register convert (x pos region = 2MB, L2/LLC resident). Epilogue: each
// block computes 128 rows of new_mem and 16 elems of y_idx.
__global__ __launch_bounds__(256, 1) void fused_kernel(
    const float* __restrict__ X, const int* __restrict__ y,
    const int* __restrict__ vis, const float* __restrict__ Mem,
    const int* __restrict__ lru_p, float* __restrict__ Csim,
    float* __restrict__ out_y, float* __restrict__ out_mem) {
  __shared__ short ldsA[2][128 * 128];  // 64 KB A double-buffer (bf16)
  __shared__ short ldsB[128 * 128];     // 32 KB resident B band (bf16)

  const int t = threadIdx.x;
  const int lane = t & 63, wv = t >> 6;
  const int wr = wv >> 1, wc = wv & 1;
  const int la = lane & 31, lb = lane >> 5;
  const int b = blockIdx.x;
  const int n0 = b * 128;

  // staging geometry: each thread converts half a row (64 f32)
  const int srow = t >> 1;
  const int scol = (t & 1) * 64;
  const int sslot0 = scol >> 3;  // first 16B slot (0 or 8)

  // x row base of sim row-panel k (128 contiguous x rows, never crosses batch)
  auto apanel = [&](int k) -> const float* {
    return X + ((size_t)(k >> 2) * 1024 + (size_t)(k & 3) * 128) * DDIM;
  };

  auto cvt_store = [&](const f32x4* v, short* dst) {
#pragma unroll
    for (int j = 0; j < 8; ++j) {
      short8 w = cvt8(v[2 * j], v[2 * j + 1]);
      const int ss = (sslot0 + j) ^ (srow & 15);  // XOR-swizzled slot
      *(short8*)&dst[srow * 128 + ss * 8] = w;
    }
  };

  // ---- prologue: convert B band + A panel 0 into LDS ----
  {
    f32x4 vb[16], va[16];
    const f32x4* pb = (const f32x4*)(Mem + (size_t)(n0 + srow) * DDIM + scol);
    const f32x4* pa = (const f32x4*)(apanel(0) + (size_t)srow * DDIM + scol);
#pragma unroll
    for (int j = 0; j < 16; ++j) vb[j] = pb[j];
#pragma unroll
    for (int j = 0; j < 16; ++j) va[j] = pa[j];
    cvt_store(vb, ldsB);
    cvt_store(va, ldsA[0]);
  }
  asm volatile("s_waitcnt lgkmcnt(0)" ::: "memory");
  __builtin_amdgcn_s_barrier();
  __builtin_amdgcn_sched_barrier(0);

  // ---- hoist B fragments to registers (64 VGPR) ----
  short8 bfr[8][2];
#pragma unroll
  for (int kk = 0; kk < 8; ++kk)
#pragma unroll
    for (int n2 = 0; n2 < 2; ++n2) {
      const int row = wc * 64 + n2 * 32 + la;
      const int ss = ((kk * 2 + lb) ^ (row & 15)) * 8;
      bfr[kk][n2] = *(const short8*)&ldsB[row * 128 + ss];
    }

  int p = 0;
  for (int k = 0; k < NK_STEPS; ++k) {
    // issue next panel's f32 loads early (hide latency under compute+stores)
    f32x4 vnext[16];
    if (k + 1 < NK_STEPS) {
      const f32x4* pn = (const f32x4*)(apanel(k + 1) + (size_t)srow * DDIM + scol);
#pragma unroll
      for (int j = 0; j < 16; ++j) vnext[j] = pn[j];
    }

    // ---- compute from ldsA[p] ----
    f32x16 acc[2][2] = {};
#pragma unroll
    for (int kk = 0; kk < 8; ++kk) {
      short8 af[2];
#pragma unroll
      for (int m2 = 0; m2 < 2; ++m2) {
        const int row = wr * 64 + m2 * 32 + la;
        const int ss = ((kk * 2 + lb) ^ (row & 15)) * 8;
        af[m2] = *(const short8*)&ldsA[p][row * 128 + ss];
      }
#pragma unroll
      for (int m2 = 0; m2 < 2; ++m2)
#pragma unroll
        for (int n2 = 0; n2 < 2; ++n2)
          acc[m2][n2] = __builtin_amdgcn_mfma_f32_32x32x16_bf16(
              af[m2], bfr[kk][n2], acc[m2][n2], 0, 0, 0);
    }

    // ---- store row-panel k (non-temporal: streaming, never re-read) ----
    const int m0 = k * 128;
#pragma unroll
    for (int m2 = 0; m2 < 2; ++m2) {
#pragma unroll
      for (int n2 = 0; n2 < 2; ++n2) {
        const int col = n0 + wc * 64 + n2 * 32 + la;
        const int rbase = m0 + wr * 64 + m2 * 32 + lb * 4;
#pragma unroll
        for (int r = 0; r < 16; ++r) {
          const int row = rbase + (r & 3) + 8 * (r >> 2);
          __builtin_nontemporal_store(acc[m2][n2][r],
                                      &Csim[(size_t)row * NLEM + col]);
        }
      }
    }

    // ---- convert + ds_write next A panel; barrier WITHOUT vmcnt drain ----
    if (k + 1 < NK_STEPS) {
      cvt_store(vnext, ldsA[p ^ 1]);
      asm volatile("s_waitcnt lgkmcnt(0)" ::: "memory");
      __builtin_amdgcn_s_barrier();
      __builtin_amdgcn_sched_barrier(0);
    }
    p ^= 1;
  }

  // ---- epilogue: new_mem rows [b*128, b*128+128) + y slice ----
  const int start = NPOS + lru_p[0] * (NNEG * BATCH);
#pragma unroll 1
  for (int i = 0; i < 32; ++i)
    newmem_row(b * 128 + wv * 32 + i, lane, X, vis, Mem, start, out_mem);
  if (t < 16) out_y[b * 16 + t] = (float)y[b * 16 + t];
}

// ==== one-shot convert-GEMM for the small noise output ====
__global__ __launch_bounds__(256) void gemm_conv_kernel(
    const float* __restrict__ X, const float* __restrict__ Bm,
    float* __restrict__ C, int ldc, int a_off) {
  __shared__ short lds[2 * 128 * 128];
  short* ldsA = lds;
  short* ldsB = lds + 128 * 128;
  const int t = threadIdx.x;
  const int m0 = blockIdx.x * 128;
  const int n0 = blockIdx.y * 128;
  const int slot = t & 15;
  const int rsub = t >> 4;
#pragma unroll
  for (int it = 0; it < 8; ++it) {
    const int row = it * 16 + rsub;
    const int gr = m0 + row;
    const int xrow = ((gr >> 9) << 10) + (gr & 511) + a_off;
    const f32x4* pa = (const f32x4*)(X + (size_t)xrow * DDIM + slot * 8);
    const f32x4* pb = (const f32x4*)(Bm + (size_t)(n0 + row) * DDIM + slot * 8);
    short8 wa = cvt8(pa[0], pa[1]);
    short8 wb = cvt8(pb[0], pb[1]);
    const int ss = (slot ^ (row & 15)) * 8;
    *(short8*)&ldsA[row * 128 + ss] = wa;
    *(short8*)&ldsB[row * 128 + ss] = wb;
  }
  __syncthreads();
  const int lane = t & 63;
  const int wv = t >> 6;
  const int wr = wv >> 1, wc = wv & 1;
  const int la = lane & 31, lb = lane >> 5;
  f32x16 acc[2][2] = {};
#pragma unroll
  for (int kk = 0; kk < 8; ++kk) {
    short8 af[2], bfr[2];
#pragma unroll
    for (int m2 = 0; m2 < 2; ++m2) {
      const int row = wr * 64 + m2 * 32 + la;
      const int ss = ((kk * 2 + lb) ^ (row & 15)) * 8;
      af[m2] = *(const short8*)&ldsA[row * 128 + ss];
    }
#pragma unroll
    for (int n2 = 0; n2 < 2; ++n2) {
      const int row = wc * 64 + n2 * 32 + la;
      const int ss = ((kk * 2 + lb) ^ (row & 15)) * 8;
      bfr[n2] = *(const short8*)&ldsB[row * 128 + ss];
    }
#pragma unroll
    for (int m2 = 0; m2 < 2; ++m2)
#pragma unroll
      for (int n2 = 0; n2 < 2; ++n2)
        acc[m2][n2] = __builtin_amdgcn_mfma_f32_32x32x16_bf16(
            af[m2], bfr[n2], acc[m2][n2], 0, 0, 0);
  }
#pragma unroll
  for (int m2 = 0; m2 < 2; ++m2)
#pragma unroll
    for (int n2 = 0; n2 < 2; ++n2) {
      const int col = n0 + wc * 64 + n2 * 32 + la;
      const int rbase = m0 + wr * 64 + m2 * 32 + lb * 4;
#pragma unroll
      for (int r = 0; r < 16; ++r) {
        const int row = rbase + (r & 3) + 8 * (r >> 2);
        C[(size_t)row * ldc + col] = acc[m2][n2][r];
      }
    }
}

extern "C" void kernel_launch(void* const* d_in, const int* in_sizes, int n_in,
                              void* d_out, int out_size, void* d_ws, size_t ws_size,
                              hipStream_t stream) {
  const float* x = (const float*)d_in[0];
  const int* y = (const int*)d_in[1];
  const int* visible = (const int*)d_in[2];
  const float* memory = (const float*)d_in[3];
  const int* lru = (const int*)d_in[4];
  float* out = (float*)d_out;

  const size_t OFF_Y = (size_t)BATCH * NPOS * NLEM;
  const size_t OFF_NOISE = OFF_Y + (size_t)BATCH * NPOS;
  const size_t OFF_MEM = OFF_NOISE + (size_t)BATCH * NNEG * NPOS;

  // noise: small one-shot (also warms x-neg + memory[:512] into LLC)
  gemm_conv_kernel<<<dim3(32, 4), 256, 0, stream>>>(x, memory, out + OFF_NOISE,
                                                    NPOS, NPOS);
  // everything else in one persistent kernel (no workspace needed)
  fused_kernel<<<256, 256, 0, stream>>>(x, y, visible, memory, lru, out,
                                        out + OFF_Y, out + OFF_MEM);
}

// Round 6
// 154.056 us; speedup vs baseline: 1.0802x; 1.0802x over previous
//
#include <hip/hip_runtime.h>
#include <hip/hip_bf16.h>
#include <cstdint>

#define NPOS 512
#define NNEG 512
#define BATCH 8
#define DDIM 128
#define NLEM 32768
#define NX_ELEM (BATCH * (NPOS + NNEG) * DDIM)  // 1048576
#define NM512_ELEM (NPOS * DDIM)                // 65536
#define NK_STEPS 32

typedef __attribute__((ext_vector_type(4))) float f32x4;
typedef __attribute__((ext_vector_type(16))) float f32x16;
typedef __attribute__((ext_vector_type(8))) short short8;

__device__ __forceinline__ unsigned short f2bf(float f) {
  unsigned u = __float_as_uint(f);
  u = (u + 0x7FFFu + ((u >> 16) & 1u)) >> 16;
  return (unsigned short)u;
}

__device__ __forceinline__ short8 cvt8(f32x4 a0, f32x4 a1) {
  short8 w;
  w[0] = (short)f2bf(a0[0]); w[1] = (short)f2bf(a0[1]);
  w[2] = (short)f2bf(a0[2]); w[3] = (short)f2bf(a0[3]);
  w[4] = (short)f2bf(a1[0]); w[5] = (short)f2bf(a1[1]);
  w[6] = (short)f2bf(a1[2]); w[7] = (short)f2bf(a1[3]);
  return w;
}

__device__ __forceinline__ void async16(const void* g, void* l) {
  __builtin_amdgcn_global_load_lds(
      (const __attribute__((address_space(1))) unsigned int*)g,
      (__attribute__((address_space(3))) unsigned int*)l, 16, 0, 0);
}

// ---- shared newmem row logic (one wave per row, exact f32) ----
__device__ __forceinline__ void newmem_row(int r, int lane, const float* __restrict__ X,
                                           const int* __restrict__ vis,
                                           const float* __restrict__ Mem, int start,
                                           float* __restrict__ out) {
  const int d0 = lane, d1 = lane + 64;
  float v0, v1;
  if (r < NPOS) {
    const float s0 = Mem[(size_t)r * DDIM + d0];
    const float s1 = Mem[(size_t)r * DDIM + d1];
    float a0 = 0.f, a1 = 0.f;
#pragma unroll
    for (int b = 0; b < BATCH; ++b) {
      const float w = (float)vis[b * NPOS + r];
      const float* px = X + (size_t)(b * (NPOS + NNEG) + r) * DDIM;
      a0 += w * px[d0];
      a1 += w * px[d1];
    }
    v0 = 0.5f * s0 + 0.0625f * a0;
    v1 = 0.5f * s1 + 0.0625f * a1;
  } else if (r >= start && r < start + BATCH * NNEG) {
    const int q = r - start;
    const int b = q >> 9, n = q & 511;
    const float* px = X + (size_t)(b * (NPOS + NNEG) + NPOS + n) * DDIM;
    v0 = px[d0];
    v1 = px[d1];
  } else {
    v0 = Mem[(size_t)r * DDIM + d0];
    v1 = Mem[(size_t)r * DDIM + d1];
  }
  float s = v0 * v0 + v1 * v1;
#pragma unroll
  for (int off = 32; off; off >>= 1) s += __shfl_xor(s, off, 64);
  const float inv = 1.0f / fmaxf(sqrtf(s), 1e-12f);
  out[(size_t)r * DDIM + d0] = v0 * inv;
  out[(size_t)r * DDIM + d1] = v1 * inv;
}

// ==== prep: bf16-convert x (all rows) + memory[:512]; write y_idx ====
// blocks: [0,512) x | [512,544) mem512 | [544,560) y
__global__ __launch_bounds__(256) void prep_kernel(
    const float* __restrict__ X, const int* __restrict__ y,
    const float* __restrict__ Mem, unsigned short* __restrict__ xb,
    unsigned short* __restrict__ mb512, float* __restrict__ out_y) {
  const int blk = blockIdx.x;
  if (blk < 512) {
    const size_t i = ((size_t)blk * 256 + threadIdx.x) * 8;
    *(short8*)(xb + i) = cvt8(*(const f32x4*)(X + i), *(const f32x4*)(X + i + 4));
  } else if (blk < 544) {
    const size_t i = ((size_t)(blk - 512) * 256 + threadIdx.x) * 8;
    *(short8*)(mb512 + i) = cvt8(*(const f32x4*)(Mem + i), *(const f32x4*)(Mem + i + 4));
  } else {
    const int i = (blk - 544) * 256 + threadIdx.x;
    out_y[i] = (float)y[i];
  }
}

// MFMA compute from one A tile + reg-resident B frags, store a 128x128 panel.
__device__ __forceinline__ void tile_compute_store(
    const short* Atile, const short8 bfr[8][2], float* __restrict__ C, int ldc,
    int m0, int n0c, int wr, int wc, int la, int lb) {
  f32x16 acc[2][2] = {};
#pragma unroll
  for (int kk = 0; kk < 8; ++kk) {
    short8 af[2];
#pragma unroll
    for (int m2 = 0; m2 < 2; ++m2) {
      const int row = wr * 64 + m2 * 32 + la;
      const int ss = ((kk * 2 + lb) ^ (row & 15)) * 8;
      af[m2] = *(const short8*)&Atile[row * 128 + ss];
    }
#pragma unroll
    for (int m2 = 0; m2 < 2; ++m2)
#pragma unroll
      for (int n2 = 0; n2 < 2; ++n2)
        acc[m2][n2] = __builtin_amdgcn_mfma_f32_32x32x16_bf16(
            af[m2], bfr[kk][n2], acc[m2][n2], 0, 0, 0);
  }
#pragma unroll
  for (int m2 = 0; m2 < 2; ++m2)
#pragma unroll
    for (int n2 = 0; n2 < 2; ++n2) {
      const int col = n0c + wc * 64 + n2 * 32 + la;
      const int rbase = m0 + wr * 64 + m2 * 32 + lb * 4;
#pragma unroll
      for (int r = 0; r < 16; ++r) {
        const int row = rbase + (r & 3) + 8 * (r >> 2);
        C[(size_t)row * ldc + col] = acc[m2][n2][r];
      }
    }
}

__device__ __forceinline__ void hoist_b(const short* Btile, short8 bfr[8][2],
                                        int wc, int la, int lb) {
#pragma unroll
  for (int kk = 0; kk < 8; ++kk)
#pragma unroll
    for (int n2 = 0; n2 < 2; ++n2) {
      const int row = wc * 64 + n2 * 32 + la;
      const int ss = ((kk * 2 + lb) ^ (row & 15)) * 8;
      bfr[kk][n2] = *(const short8*)&Btile[row * 128 + ss];
    }
}

// ==== fused persistent kernel ====
// Block b owns sim column band n0=b*128. B band converted from f32 in
// prologue (reg->LDS->reg frags). A panels DMA'd from bf16 xb; all blocks
// write the same contiguous 16MB row band per step. Step 31 additionally
// stages a noise tile for blocks b<128 (computed after the sim loop).
// Epilogue: 128 rows of new_mem per block + y handled by prep.
__global__ __launch_bounds__(256, 1) void fused_kernel(
    const float* __restrict__ X, const int* __restrict__ vis,
    const float* __restrict__ Mem, const int* __restrict__ lru_p,
    const unsigned short* __restrict__ xb, const unsigned short* __restrict__ mb512,
    float* __restrict__ Csim, float* __restrict__ Cnoise,
    float* __restrict__ out_mem) {
  __shared__ short ldsA[2][128 * 128];  // 64 KB A double-buffer
  __shared__ short ldsB[128 * 128];     // 32 KB B (band in prologue, noise B late)

  const int t = threadIdx.x;
  const int lane = t & 63, wv = t >> 6;
  const int rl = lane >> 4, slot = lane & 15;
  const int wr = wv >> 1, wc = wv & 1;
  const int la = lane & 31, lb = lane >> 5;
  const int b = blockIdx.x;
  const int n0 = b * 128;

  auto stage_tile = [&](short* dst, const unsigned short* src, int rowbase) {
#pragma unroll
    for (int i = 0; i < 8; ++i) {
      const int rowb = wv * 32 + i * 4;  // wave-uniform base row
      const int row = rowb + rl;
      const int ss = slot ^ (row & 15);  // inverse-swizzled source (involution)
      async16(src + (size_t)(rowbase + row) * DDIM + ss * 8, &dst[rowb * 128]);
    }
  };

  // ---- prologue: A(0) via DMA; B band converted from f32 Mem ----
  stage_tile(ldsA[0], xb, 0);  // sim panel 0 = x rows [0,128) (batch 0 pos)
  {
    const int srow = t >> 1, scol = (t & 1) * 64, sslot0 = scol >> 3;
    f32x4 vb[16];
    const f32x4* pb = (const f32x4*)(Mem + (size_t)(n0 + srow) * DDIM + scol);
#pragma unroll
    for (int j = 0; j < 16; ++j) vb[j] = pb[j];
#pragma unroll
    for (int j = 0; j < 8; ++j) {
      short8 w = cvt8(vb[2 * j], vb[2 * j + 1]);
      const int ss = (sslot0 + j) ^ (srow & 15);
      *(short8*)&ldsB[srow * 128 + ss * 8] = w;
    }
  }
  asm volatile("s_waitcnt vmcnt(0) lgkmcnt(0)" ::: "memory");
  __builtin_amdgcn_s_barrier();
  __builtin_amdgcn_sched_barrier(0);

  short8 bfr[8][2];
  hoist_b(ldsB, bfr, wc, la, lb);  // B frags -> 32 VGPR; ldsB free afterwards

  int p = 0;
  for (int k = 0; k < NK_STEPS; ++k) {
    // stage next work BEFORE this step's stores (counted-vmcnt guarantee)
    if (k + 1 < NK_STEPS) {
      const int kn = k + 1;
      stage_tile(ldsA[p ^ 1], xb, (kn >> 2) * 1024 + (kn & 3) * 128);
    } else if (b < 128) {
      const int rp = b >> 2, cb = b & 3;  // noise row-panel / col-band
      stage_tile(ldsA[p ^ 1], xb, (rp >> 2) * 1024 + 512 + (rp & 3) * 128);
      stage_tile(ldsB, mb512, cb * 128);
    }

    tile_compute_store(ldsA[p], bfr, Csim, NLEM, k * 128, n0, wr, wc, la, lb);

    // vmcnt(60) < 64 stores issued after the <=16 staging loads => loads
    // retired; ~60 stores keep draining across the barrier.
    if (k + 1 < NK_STEPS || b < 128) {
      asm volatile("s_waitcnt vmcnt(60)" ::: "memory");
      __builtin_amdgcn_s_barrier();
      __builtin_amdgcn_sched_barrier(0);
    }
    p ^= 1;
  }

  // ---- noise tile (blocks 0..127): A' in ldsA[p], B' in ldsB ----
  if (b < 128) {
    const int rp = b >> 2, cb = b & 3;
    short8 bfr2[8][2];
    hoist_b(ldsB, bfr2, wc, la, lb);
    tile_compute_store(ldsA[p], bfr2, Cnoise, NPOS, rp * 128, cb * 128,
                       wr, wc, la, lb);
  }

  // ---- epilogue: new_mem rows [b*128, b*128+128) ----
  const int start = NPOS + lru_p[0] * (NNEG * BATCH);
#pragma unroll 1
  for (int i = 0; i < 32; ++i)
    newmem_row(b * 128 + wv * 32 + i, lane, X, vis, Mem, start, out_mem);
}

// ================= fallback path (used only if ws too small) ====
__global__ __launch_bounds__(256) void gemm_conv_kernel(
    const float* __restrict__ X, const float* __restrict__ Bm,
    float* __restrict__ C, int ldc, int a_off) {
  __shared__ short lds[2 * 128 * 128];
  short* ldsA = lds;
  short* ldsB = lds + 128 * 128;
  const int t = threadIdx.x;
  const int m0 = blockIdx.x * 128;
  const int n0 = blockIdx.y * 128;
  const int slot = t & 15;
  const int rsub = t >> 4;
#pragma unroll
  for (int it = 0; it < 8; ++it) {
    const int row = it * 16 + rsub;
    const int gr = m0 + row;
    const int xrow = ((gr >> 9) << 10) + (gr & 511) + a_off;
    const f32x4* pa = (const f32x4*)(X + (size_t)xrow * DDIM + slot * 8);
    const f32x4* pb = (const f32x4*)(Bm + (size_t)(n0 + row) * DDIM + slot * 8);
    short8 wa = cvt8(pa[0], pa[1]);
    short8 wb = cvt8(pb[0], pb[1]);
    const int ss = (slot ^ (row & 15)) * 8;
    *(short8*)&ldsA[row * 128 + ss] = wa;
    *(short8*)&ldsB[row * 128 + ss] = wb;
  }
  __syncthreads();
  const int lane = t & 63;
  const int wv = t >> 6;
  const int wr = wv >> 1, wc = wv & 1;
  const int la = lane & 31, lb = lane >> 5;
  short8 bfr[8][2];
  hoist_b(ldsB, bfr, wc, la, lb);
  tile_compute_store(ldsA, bfr, C, ldc, m0, n0, wr, wc, la, lb);
}

__global__ void y_kernel(const int* __restrict__ y, float* __restrict__ out) {
  const int i = blockIdx.x * blockDim.x + threadIdx.x;
  if (i < BATCH * NPOS) out[i] = (float)y[i];
}

__global__ __launch_bounds__(256) void newmem_kernel(
    const float* __restrict__ X, const int* __restrict__ vis,
    const float* __restrict__ Mem, const int* __restrict__ lru_p,
    float* __restrict__ out) {
  const int r = blockIdx.x * 4 + (threadIdx.x >> 6);
  const int start = NPOS + lru_p[0] * (NNEG * BATCH);
  newmem_row(r, threadIdx.x & 63, X, vis, Mem, start, out);
}

extern "C" void kernel_launch(void* const* d_in, const int* in_sizes, int n_in,
                              void* d_out, int out_size, void* d_ws, size_t ws_size,
                              hipStream_t stream) {
  const float* x = (const float*)d_in[0];
  const int* y = (const int*)d_in[1];
  const int* visible = (const int*)d_in[2];
  const float* memory = (const float*)d_in[3];
  const int* lru = (const int*)d_in[4];
  float* out = (float*)d_out;

  const size_t OFF_Y = (size_t)BATCH * NPOS * NLEM;
  const size_t OFF_NOISE = OFF_Y + (size_t)BATCH * NPOS;
  const size_t OFF_MEM = OFF_NOISE + (size_t)BATCH * NNEG * NPOS;

  const size_t need = (size_t)(NX_ELEM + NM512_ELEM) * 2;  // 2.2 MB
  if (ws_size >= need) {
    unsigned short* xb = (unsigned short*)d_ws;
    unsigned short* mb512 = xb + NX_ELEM;
    prep_kernel<<<560, 256, 0, stream>>>(x, y, memory, xb, mb512, out + OFF_Y);
    fused_kernel<<<256, 256, 0, stream>>>(x, visible, memory, lru, xb, mb512,
                                          out, out + OFF_NOISE, out + OFF_MEM);
  } else {
    gemm_conv_kernel<<<dim3(32, 256), 256, 0, stream>>>(x, memory, out, NLEM, 0);
    gemm_conv_kernel<<<dim3(32, 4), 256, 0, stream>>>(x, memory, out + OFF_NOISE, NPOS, NPOS);
    y_kernel<<<16, 256, 0, stream>>>(y, out + OFF_Y);
    newmem_kernel<<<NLEM / 4, 256, 0, stream>>>(x, visible, memory, lru, out + OFF_MEM);
  }
}

// Round 7
// 142.997 us; speedup vs baseline: 1.1637x; 1.0773x over previous
//
#include <hip/hip_runtime.h>
#include <hip/hip_bf16.h>
#include <cstdint>

#define NPOS 512
#define NNEG 512
#define BATCH 8
#define DDIM 128
#define NLEM 32768
#define NX_ELEM (BATCH * (NPOS + NNEG) * DDIM)  // 1048576
#define NM_ELEM (NLEM * DDIM)                   // 4194304
#define NK_STEPS 32

typedef __attribute__((ext_vector_type(4))) float f32x4;
typedef __attribute__((ext_vector_type(16))) float f32x16;
typedef __attribute__((ext_vector_type(8))) short short8;

__device__ __forceinline__ unsigned short f2bf(float f) {
  unsigned u = __float_as_uint(f);
  u = (u + 0x7FFFu + ((u >> 16) & 1u)) >> 16;
  return (unsigned short)u;
}

__device__ __forceinline__ short8 cvt8(f32x4 a0, f32x4 a1) {
  short8 w;
  w[0] = (short)f2bf(a0[0]); w[1] = (short)f2bf(a0[1]);
  w[2] = (short)f2bf(a0[2]); w[3] = (short)f2bf(a0[3]);
  w[4] = (short)f2bf(a1[0]); w[5] = (short)f2bf(a1[1]);
  w[6] = (short)f2bf(a1[2]); w[7] = (short)f2bf(a1[3]);
  return w;
}

__device__ __forceinline__ void async16(const void* g, void* l) {
  __builtin_amdgcn_global_load_lds(
      (const __attribute__((address_space(1))) unsigned int*)g,
      (__attribute__((address_space(3))) unsigned int*)l, 16, 0, 0);
}

// ---- shared newmem row logic (one wave per row, exact f32) ----
__device__ __forceinline__ void newmem_row(int r, int lane, const float* __restrict__ X,
                                           const int* __restrict__ vis,
                                           const float* __restrict__ Mem, int start,
                                           float* __restrict__ out) {
  const int d0 = lane, d1 = lane + 64;
  float v0, v1;
  if (r < NPOS) {
    const float s0 = Mem[(size_t)r * DDIM + d0];
    const float s1 = Mem[(size_t)r * DDIM + d1];
    float a0 = 0.f, a1 = 0.f;
#pragma unroll
    for (int b = 0; b < BATCH; ++b) {
      const float w = (float)vis[b * NPOS + r];
      const float* px = X + (size_t)(b * (NPOS + NNEG) + r) * DDIM;
      a0 += w * px[d0];
      a1 += w * px[d1];
    }
    v0 = 0.5f * s0 + 0.0625f * a0;
    v1 = 0.5f * s1 + 0.0625f * a1;
  } else if (r >= start && r < start + BATCH * NNEG) {
    const int q = r - start;
    const int b = q >> 9, n = q & 511;
    const float* px = X + (size_t)(b * (NPOS + NNEG) + NPOS + n) * DDIM;
    v0 = px[d0];
    v1 = px[d1];
  } else {
    v0 = Mem[(size_t)r * DDIM + d0];
    v1 = Mem[(size_t)r * DDIM + d1];
  }
  float s = v0 * v0 + v1 * v1;
#pragma unroll
  for (int off = 32; off; off >>= 1) s += __shfl_xor(s, off, 64);
  const float inv = 1.0f / fmaxf(sqrtf(s), 1e-12f);
  out[(size_t)r * DDIM + d0] = v0 * inv;
  out[(size_t)r * DDIM + d1] = v1 * inv;
}

// ==== prep (round-2 proven): convert all x + all memory, y, newmem ====
// blocks: [0,512) x | [512,2560) mem | [2560,2576) y | [2576,10768) newmem
__global__ __launch_bounds__(256) void prep_kernel(
    const float* __restrict__ X, const int* __restrict__ y,
    const int* __restrict__ vis, const float* __restrict__ Mem,
    const int* __restrict__ lru_p, unsigned short* __restrict__ xb,
    unsigned short* __restrict__ mb, float* __restrict__ out_y,
    float* __restrict__ out_mem) {
  const int blk = blockIdx.x;
  if (blk < 512) {
    const size_t i = ((size_t)blk * 256 + threadIdx.x) * 8;
    *(short8*)(xb + i) = cvt8(*(const f32x4*)(X + i), *(const f32x4*)(X + i + 4));
  } else if (blk < 2560) {
    const size_t i = ((size_t)(blk - 512) * 256 + threadIdx.x) * 8;
    *(short8*)(mb + i) = cvt8(*(const f32x4*)(Mem + i), *(const f32x4*)(Mem + i + 4));
  } else if (blk < 2576) {
    const int i = (blk - 2560) * 256 + threadIdx.x;
    out_y[i] = (float)y[i];
  } else {
    const int r = (blk - 2576) * 4 + (threadIdx.x >> 6);
    const int start = NPOS + lru_p[0] * (NNEG * BATCH);
    newmem_row(r, threadIdx.x & 63, X, vis, Mem, start, out_mem);
  }
}

__device__ __forceinline__ void hoist_b(const short* Btile, short8 bfr[8][2],
                                        int wc, int la, int lb) {
#pragma unroll
  for (int kk = 0; kk < 8; ++kk)
#pragma unroll
    for (int n2 = 0; n2 < 2; ++n2) {
      const int row = wc * 64 + n2 * 32 + la;
      const int ss = ((kk * 2 + lb) ^ (row & 15)) * 8;
      bfr[kk][n2] = *(const short8*)&Btile[row * 128 + ss];
    }
}

__device__ __forceinline__ void tile_mfma(const short* Atile, const short8 bfr[8][2],
                                          f32x16 acc[2][2], int wr, int la, int lb) {
#pragma unroll
  for (int kk = 0; kk < 8; ++kk) {
    short8 af[2];
#pragma unroll
    for (int m2 = 0; m2 < 2; ++m2) {
      const int row = wr * 64 + m2 * 32 + la;
      const int ss = ((kk * 2 + lb) ^ (row & 15)) * 8;
      af[m2] = *(const short8*)&Atile[row * 128 + ss];
    }
#pragma unroll
    for (int m2 = 0; m2 < 2; ++m2)
#pragma unroll
      for (int n2 = 0; n2 < 2; ++n2)
        acc[m2][n2] = __builtin_amdgcn_mfma_f32_32x32x16_bf16(
            af[m2], bfr[kk][n2], acc[m2][n2], 0, 0, 0);
  }
}

// ---- LDS-transpose epilogue: stage C in LDS (two 64-row halves), store
// row-contiguous dwordx4. Each store instr writes two FULL 512B row-chunks
// (vs two scattered 128B segments with direct 4B stores).
// ldsC layout: float[64][132] (stride 132 spreads banks: bank=(4*rho+col)%32).
__device__ __forceinline__ void epilogue_store(
    float* __restrict__ ldsC, const f32x16 acc[2][2], float* __restrict__ C,
    int ldc, int m0, int n0c, int t, int wr, int wc, int la, int lb) {
  const int rg = t >> 5, l5 = t & 31;
#pragma unroll
  for (int H = 0; H < 2; ++H) {
    if (wr == H) {  // waves owning rows [64H, 64H+64) write their acc
#pragma unroll
      for (int m2 = 0; m2 < 2; ++m2)
#pragma unroll
        for (int n2 = 0; n2 < 2; ++n2) {
          const int colb = wc * 64 + n2 * 32 + la;
          const int rb = m2 * 32 + lb * 4;
#pragma unroll
          for (int r = 0; r < 16; ++r) {
            const int rho = rb + (r & 3) + 8 * (r >> 2);
            ldsC[rho * 132 + colb] = acc[m2][n2][r];
          }
        }
    }
    asm volatile("s_waitcnt lgkmcnt(0)" ::: "memory");
    __builtin_amdgcn_s_barrier();
    __builtin_amdgcn_sched_barrier(0);
    // all 256 threads: thread covers cols [4*l5, 4*l5+4) of rows rg+8i
#pragma unroll
    for (int i = 0; i < 8; ++i) {
      const int rho = rg + 8 * i;
      const f32x4 v = *(const f32x4*)&ldsC[rho * 132 + l5 * 4];
      *(f32x4*)&C[(size_t)(m0 + H * 64 + rho) * ldc + n0c + l5 * 4] = v;
    }
    if (H == 0) {  // protect ldsC before H1 writes; H1 is covered by caller
      __builtin_amdgcn_s_barrier();
      __builtin_amdgcn_sched_barrier(0);
    }
  }
}

// ==== band-persistent GEMM + folded noise tile ====
// Block b owns sim column band n0=b*128 (B resident in regs). Step k: all
// blocks write the same contiguous 16MB row band. Last step stages a noise
// tile (blocks 0..127) computed after the sim loop.
__global__ __launch_bounds__(256, 1) void gemm_band_kernel(
    const unsigned short* __restrict__ Xb, const unsigned short* __restrict__ Mb,
    float* __restrict__ Csim, float* __restrict__ Cnoise) {
  __shared__ short ldsA[2][128 * 128];  // 64 KB A double-buffer
  __shared__ short ldsB[128 * 128];     // 32 KB B (band, then noise B')
  __shared__ float ldsC[64 * 132];      // 33 KB C staging (half tile)

  const int t = threadIdx.x;
  const int lane = t & 63, wv = t >> 6;
  const int rl = lane >> 4, slot = lane & 15;
  const int wr = wv >> 1, wc = wv & 1;
  const int la = lane & 31, lb = lane >> 5;
  const int b = blockIdx.x;
  const int n0 = b * 128;

  auto stage_tile = [&](short* dst, const unsigned short* src, int rowbase) {
#pragma unroll
    for (int i = 0; i < 8; ++i) {
      const int rowb = wv * 32 + i * 4;  // wave-uniform base row
      const int row = rowb + rl;
      const int ss = slot ^ (row & 15);  // inverse-swizzled source (involution)
      async16(src + (size_t)(rowbase + row) * DDIM + ss * 8, &dst[rowb * 128]);
    }
  };

  // ---- prologue ----
  stage_tile(ldsB, Mb, n0);
  stage_tile(ldsA[0], Xb, 0);
  asm volatile("s_waitcnt vmcnt(0)" ::: "memory");
  __builtin_amdgcn_s_barrier();
  __builtin_amdgcn_sched_barrier(0);

  short8 bfr[8][2];
  hoist_b(ldsB, bfr, wc, la, lb);  // B -> 32 VGPR; ldsB free afterwards

  int p = 0;
  for (int k = 0; k < NK_STEPS; ++k) {
    // stage next work BEFORE this step's stores (counted-vmcnt guarantee)
    if (k + 1 < NK_STEPS) {
      const int kn = k + 1;
      stage_tile(ldsA[p ^ 1], Xb, (kn >> 2) * 1024 + (kn & 3) * 128);
    } else if (b < 128) {
      const int rp = b >> 2, cb = b & 3;  // noise row-panel / col-band
      stage_tile(ldsA[p ^ 1], Xb, (rp >> 2) * 1024 + 512 + (rp & 3) * 128);
      stage_tile(ldsB, Mb, cb * 128);
    }

    f32x16 acc[2][2] = {};
    tile_mfma(ldsA[p], bfr, acc, wr, la, lb);
    epilogue_store(ldsC, acc, Csim, NLEM, k * 128, n0, t, wr, wc, la, lb);

    // vmcnt(16): per step we issue <=16 loads then 16 dwordx4 stores; waiting
    // to <=16 outstanding drains all prior stores + this step's loads, while
    // this step's 16 stores keep draining across the barrier.
    if (k + 1 < NK_STEPS || b < 128) {
      asm volatile("s_waitcnt vmcnt(16)" ::: "memory");
      __builtin_amdgcn_s_barrier();
      __builtin_amdgcn_sched_barrier(0);
    }
    p ^= 1;
  }

  // ---- noise tile (blocks 0..127): A' in ldsA[p], B' in ldsB ----
  if (b < 128) {
    const int rp = b >> 2, cb = b & 3;
    short8 bfr2[8][2];
    hoist_b(ldsB, bfr2, wc, la, lb);
    f32x16 acc[2][2] = {};
    tile_mfma(ldsA[p], bfr2, acc, wr, la, lb);
    epilogue_store(ldsC, acc, Cnoise, NPOS, rp * 128, cb * 128, t, wr, wc, la, lb);
  }
}

// ================= fallback path (used only if ws too small) ====
__global__ __launch_bounds__(256) void gemm_conv_kernel(
    const float* __restrict__ X, const float* __restrict__ Bm,
    float* __restrict__ C, int ldc, int a_off) {
  __shared__ short lds[2 * 128 * 128];
  short* ldsA = lds;
  short* ldsB = lds + 128 * 128;
  const int t = threadIdx.x;
  const int m0 = blockIdx.x * 128;
  const int n0 = blockIdx.y * 128;
  const int slot = t & 15;
  const int rsub = t >> 4;
#pragma unroll
  for (int it = 0; it < 8; ++it) {
    const int row = it * 16 + rsub;
    const int gr = m0 + row;
    const int xrow = ((gr >> 9) << 10) + (gr & 511) + a_off;
    const f32x4* pa = (const f32x4*)(X + (size_t)xrow * DDIM + slot * 8);
    const f32x4* pb = (const f32x4*)(Bm + (size_t)(n0 + row) * DDIM + slot * 8);
    short8 wa = cvt8(pa[0], pa[1]);
    short8 wb = cvt8(pb[0], pb[1]);
    const int ss = (slot ^ (row & 15)) * 8;
    *(short8*)&ldsA[row * 128 + ss] = wa;
    *(short8*)&ldsB[row * 128 + ss] = wb;
  }
  __syncthreads();
  const int lane = t & 63;
  const int wv = t >> 6;
  const int wr = wv >> 1, wc = wv & 1;
  const int la = lane & 31, lb = lane >> 5;
  short8 bfr[8][2];
  hoist_b(ldsB, bfr, wc, la, lb);
  f32x16 acc[2][2] = {};
  tile_mfma(ldsA, bfr, acc, wr, la, lb);
#pragma unroll
  for (int m2 = 0; m2 < 2; ++m2)
#pragma unroll
    for (int n2 = 0; n2 < 2; ++n2) {
      const int col = n0 + wc * 64 + n2 * 32 + la;
      const int rbase = m0 + wr * 64 + m2 * 32 + lb * 4;
#pragma unroll
      for (int r = 0; r < 16; ++r) {
        const int row = rbase + (r & 3) + 8 * (r >> 2);
        C[(size_t)row * ldc + col] = acc[m2][n2][r];
      }
    }
}

__global__ void y_kernel(const int* __restrict__ y, float* __restrict__ out) {
  const int i = blockIdx.x * blockDim.x + threadIdx.x;
  if (i < BATCH * NPOS) out[i] = (float)y[i];
}

__global__ __launch_bounds__(256) void newmem_kernel(
    const float* __restrict__ X, const int* __restrict__ vis,
    const float* __restrict__ Mem, const int* __restrict__ lru_p,
    float* __restrict__ out) {
  const int r = blockIdx.x * 4 + (threadIdx.x >> 6);
  const int start = NPOS + lru_p[0] * (NNEG * BATCH);
  newmem_row(r, threadIdx.x & 63, X, vis, Mem, start, out);
}

extern "C" void kernel_launch(void* const* d_in, const int* in_sizes, int n_in,
                              void* d_out, int out_size, void* d_ws, size_t ws_size,
                              hipStream_t stream) {
  const float* x = (const float*)d_in[0];
  const int* y = (const int*)d_in[1];
  const int* visible = (const int*)d_in[2];
  const float* memory = (const float*)d_in[3];
  const int* lru = (const int*)d_in[4];
  float* out = (float*)d_out;

  const size_t OFF_Y = (size_t)BATCH * NPOS * NLEM;
  const size_t OFF_NOISE = OFF_Y + (size_t)BATCH * NPOS;
  const size_t OFF_MEM = OFF_NOISE + (size_t)BATCH * NNEG * NPOS;

  const size_t need = (size_t)(NX_ELEM + NM_ELEM) * 2;  // 10.5 MB bf16 scratch
  if (ws_size >= need) {
    unsigned short* xb = (unsigned short*)d_ws;
    unsigned short* mb = xb + NX_ELEM;
    prep_kernel<<<10768, 256, 0, stream>>>(
        x, y, visible, memory, lru, xb, mb, out + OFF_Y, out + OFF_MEM);
    gemm_band_kernel<<<256, 256, 0, stream>>>(xb, mb, out, out + OFF_NOISE);
  } else {
    gemm_conv_kernel<<<dim3(32, 256), 256, 0, stream>>>(x, memory, out, NLEM, 0);
    gemm_conv_kernel<<<dim3(32, 4), 256, 0, stream>>>(x, memory, out + OFF_NOISE, NPOS, NPOS);
    y_kernel<<<16, 256, 0, stream>>>(y, out + OFF_Y);
    newmem_kernel<<<NLEM / 4, 256, 0, stream>>>(x, visible, memory, lru, out + OFF_MEM);
  }
}

// Round 8
// 120.712 us; speedup vs baseline: 1.3785x; 1.1846x over previous
//
#include <hip/hip_runtime.h>
#include <hip/hip_bf16.h>
#include <cstdint>

#define NPOS 512
#define NNEG 512
#define BATCH 8
#define DDIM 128
#define NLEM 32768
#define NX_ELEM (BATCH * (NPOS + NNEG) * DDIM)  // 1048576
#define NM_ELEM (NLEM * DDIM)                   // 4194304

typedef __attribute__((ext_vector_type(4))) float f32x4;
typedef __attribute__((ext_vector_type(16))) float f32x16;
typedef __attribute__((ext_vector_type(8))) short short8;

__device__ __forceinline__ unsigned short f2bf(float f) {
  unsigned u = __float_as_uint(f);
  u = (u + 0x7FFFu + ((u >> 16) & 1u)) >> 16;
  return (unsigned short)u;
}

__device__ __forceinline__ short8 cvt8(f32x4 a0, f32x4 a1) {
  short8 w;
  w[0] = (short)f2bf(a0[0]); w[1] = (short)f2bf(a0[1]);
  w[2] = (short)f2bf(a0[2]); w[3] = (short)f2bf(a0[3]);
  w[4] = (short)f2bf(a1[0]); w[5] = (short)f2bf(a1[1]);
  w[6] = (short)f2bf(a1[2]); w[7] = (short)f2bf(a1[3]);
  return w;
}

__device__ __forceinline__ void async16(const void* g, void* l) {
  __builtin_amdgcn_global_load_lds(
      (const __attribute__((address_space(1))) unsigned int*)g,
      (__attribute__((address_space(3))) unsigned int*)l, 16, 0, 0);
}

// ---- shared newmem row logic (one wave per row, exact f32) ----
__device__ __forceinline__ void newmem_row(int r, int lane, const float* __restrict__ X,
                                           const int* __restrict__ vis,
                                           const float* __restrict__ Mem, int start,
                                           float* __restrict__ out) {
  const int d0 = lane, d1 = lane + 64;
  float v0, v1;
  if (r < NPOS) {
    const float s0 = Mem[(size_t)r * DDIM + d0];
    const float s1 = Mem[(size_t)r * DDIM + d1];
    float a0 = 0.f, a1 = 0.f;
#pragma unroll
    for (int b = 0; b < BATCH; ++b) {
      const float w = (float)vis[b * NPOS + r];
      const float* px = X + (size_t)(b * (NPOS + NNEG) + r) * DDIM;
      a0 += w * px[d0];
      a1 += w * px[d1];
    }
    v0 = 0.5f * s0 + 0.0625f * a0;
    v1 = 0.5f * s1 + 0.0625f * a1;
  } else if (r >= start && r < start + BATCH * NNEG) {
    const int q = r - start;
    const int b = q >> 9, n = q & 511;
    const float* px = X + (size_t)(b * (NPOS + NNEG) + NPOS + n) * DDIM;
    v0 = px[d0];
    v1 = px[d1];
  } else {
    v0 = Mem[(size_t)r * DDIM + d0];
    v1 = Mem[(size_t)r * DDIM + d1];
  }
  float s = v0 * v0 + v1 * v1;
#pragma unroll
  for (int off = 32; off; off >>= 1) s += __shfl_xor(s, off, 64);
  const float inv = 1.0f / fmaxf(sqrtf(s), 1e-12f);
  out[(size_t)r * DDIM + d0] = v0 * inv;
  out[(size_t)r * DDIM + d1] = v1 * inv;
}

// ==== prep (proven): convert all x + all memory, y, newmem ====
__global__ __launch_bounds__(256) void prep_kernel(
    const float* __restrict__ X, const int* __restrict__ y,
    const int* __restrict__ vis, const float* __restrict__ Mem,
    const int* __restrict__ lru_p, unsigned short* __restrict__ xb,
    unsigned short* __restrict__ mb, float* __restrict__ out_y,
    float* __restrict__ out_mem) {
  const int blk = blockIdx.x;
  if (blk < 512) {
    const size_t i = ((size_t)blk * 256 + threadIdx.x) * 8;
    *(short8*)(xb + i) = cvt8(*(const f32x4*)(X + i), *(const f32x4*)(X + i + 4));
  } else if (blk < 2560) {
    const size_t i = ((size_t)(blk - 512) * 256 + threadIdx.x) * 8;
    *(short8*)(mb + i) = cvt8(*(const f32x4*)(Mem + i), *(const f32x4*)(Mem + i + 4));
  } else if (blk < 2576) {
    const int i = (blk - 2560) * 256 + threadIdx.x;
    out_y[i] = (float)y[i];
  } else {
    const int r = (blk - 2576) * 4 + (threadIdx.x >> 6);
    const int start = NPOS + lru_p[0] * (NNEG * BATCH);
    newmem_row(r, threadIdx.x & 63, X, vis, Mem, start, out_mem);
  }
}

__device__ __forceinline__ void hoist_b(const short* Btile, short8 bfr[8][2],
                                        int wc, int la, int lb) {
#pragma unroll
  for (int kk = 0; kk < 8; ++kk)
#pragma unroll
    for (int n2 = 0; n2 < 2; ++n2) {
      const int row = wc * 64 + n2 * 32 + la;
      const int ss = ((kk * 2 + lb) ^ (row & 15)) * 8;
      bfr[kk][n2] = *(const short8*)&Btile[row * 128 + ss];
    }
}

__device__ __forceinline__ void tile_mfma(const short* Atile, const short8 bfr[8][2],
                                          f32x16 acc[2][2], int wr, int la, int lb) {
#pragma unroll
  for (int kk = 0; kk < 8; ++kk) {
    short8 af[2];
#pragma unroll
    for (int m2 = 0; m2 < 2; ++m2) {
      const int row = wr * 64 + m2 * 32 + la;
      const int ss = ((kk * 2 + lb) ^ (row & 15)) * 8;
      af[m2] = *(const short8*)&Atile[row * 128 + ss];
    }
#pragma unroll
    for (int m2 = 0; m2 < 2; ++m2)
#pragma unroll
      for (int n2 = 0; n2 < 2; ++n2)
        acc[m2][n2] = __builtin_amdgcn_mfma_f32_32x32x16_bf16(
            af[m2], bfr[kk][n2], acc[m2][n2], 0, 0, 0);
  }
}

__device__ __forceinline__ void store_acc(const f32x16 acc[2][2],
                                          float* __restrict__ C, int ldc, int m0,
                                          int n0c, int wr, int wc, int la, int lb) {
#pragma unroll
  for (int m2 = 0; m2 < 2; ++m2)
#pragma unroll
    for (int n2 = 0; n2 < 2; ++n2) {
      const int col = n0c + wc * 64 + n2 * 32 + la;
      const int rbase = m0 + wr * 64 + m2 * 32 + lb * 4;
#pragma unroll
      for (int r = 0; r < 16; ++r) {
        const int row = rbase + (r & 3) + 8 * (r >> 2);
        C[(size_t)row * ldc + col] = acc[m2][n2][r];
      }
    }
}

// ==== half-band persistent GEMM, 2 blocks/CU (64 KB LDS exactly) ====
// Block blk: band = blk>>1 (cols [band*128,+128)), h = blk&1 -> sim row
// panels K = h*16 + 0..15. B staged once through ldsA[1], hoisted to regs.
// Blocks 0..127 additionally compute one noise tile at the tail.
__global__ __launch_bounds__(256, 2) void gemm_band2_kernel(
    const unsigned short* __restrict__ Xb, const unsigned short* __restrict__ Mb,
    float* __restrict__ Csim, float* __restrict__ Cnoise) {
  __shared__ short ldsA[2][128 * 128];  // exactly 64 KB

  const int t = threadIdx.x;
  const int lane = t & 63, wv = t >> 6;
  const int rl = lane >> 4, slot = lane & 15;
  const int wr = wv >> 1, wc = wv & 1;
  const int la = lane & 31, lb = lane >> 5;
  const int blk = blockIdx.x;
  const int band = blk >> 1, h = blk & 1;
  const int n0 = band * 128;

  auto stage_tile = [&](short* dst, const unsigned short* src, int rowbase) {
#pragma unroll
    for (int i = 0; i < 8; ++i) {
      const int rowb = wv * 32 + i * 4;  // wave-uniform base row
      const int row = rowb + rl;
      const int ss = slot ^ (row & 15);  // inverse-swizzled source (involution)
      async16(src + (size_t)(rowbase + row) * DDIM + ss * 8, &dst[rowb * 128]);
    }
  };

  // ---- prologue: B through ldsA[1]; first A panel into ldsA[0] ----
  stage_tile(ldsA[1], Mb, n0);
  {
    const int K0 = h * 16;
    stage_tile(ldsA[0], Xb, (K0 >> 2) * 1024 + (K0 & 3) * 128);
  }
  asm volatile("s_waitcnt vmcnt(0)" ::: "memory");
  __builtin_amdgcn_s_barrier();
  __builtin_amdgcn_sched_barrier(0);

  short8 bfr[8][2];
  hoist_b(ldsA[1], bfr, wc, la, lb);  // B -> 32 VGPR
  // all hoist ds_reads must finish before k=0 DMAs into ldsA[1]
  asm volatile("s_waitcnt lgkmcnt(0)" ::: "memory");
  __builtin_amdgcn_s_barrier();
  __builtin_amdgcn_sched_barrier(0);

  int p = 0;
  for (int k = 0; k < 16; ++k) {
    // stage next panel BEFORE this step's stores (counted-vmcnt guarantee)
    if (k + 1 < 16) {
      const int K = h * 16 + k + 1;
      stage_tile(ldsA[p ^ 1], Xb, (K >> 2) * 1024 + (K & 3) * 128);
    }

    f32x16 acc[2][2] = {};
    tile_mfma(ldsA[p], bfr, acc, wr, la, lb);
    store_acc(acc, Csim, NLEM, (h * 16 + k) * 128, n0, wr, wc, la, lb);

    // vmcnt(60) < 64 stores issued after the 8 staging loads => loads
    // retired; ~60 stores keep draining across the barrier.
    asm volatile("s_waitcnt vmcnt(60)" ::: "memory");
    __builtin_amdgcn_s_barrier();
    __builtin_amdgcn_sched_barrier(0);
    p ^= 1;
  }

  // ---- noise tail: blocks 0..127 each do one 128x128 noise tile ----
  if (blk < 128) {
    const int rp = blk >> 2, cb = blk & 3;  // row panel 0..31, col band 0..3
    stage_tile(ldsA[p ^ 1], Xb, (rp >> 2) * 1024 + 512 + (rp & 3) * 128);
    stage_tile(ldsA[p], Mb, cb * 128);
    asm volatile("s_waitcnt vmcnt(0)" ::: "memory");
    __builtin_amdgcn_s_barrier();
    __builtin_amdgcn_sched_barrier(0);
    short8 bfr2[8][2];
    hoist_b(ldsA[p], bfr2, wc, la, lb);
    f32x16 acc[2][2] = {};
    tile_mfma(ldsA[p ^ 1], bfr2, acc, wr, la, lb);
    store_acc(acc, Cnoise, NPOS, rp * 128, cb * 128, wr, wc, la, lb);
  }
}

// ================= fallback path (used only if ws too small) ====
__global__ __launch_bounds__(256) void gemm_conv_kernel(
    const float* __restrict__ X, const float* __restrict__ Bm,
    float* __restrict__ C, int ldc, int a_off) {
  __shared__ short lds[2 * 128 * 128];
  short* ldsA = lds;
  short* ldsB = lds + 128 * 128;
  const int t = threadIdx.x;
  const int m0 = blockIdx.x * 128;
  const int n0 = blockIdx.y * 128;
  const int slot = t & 15;
  const int rsub = t >> 4;
#pragma unroll
  for (int it = 0; it < 8; ++it) {
    const int row = it * 16 + rsub;
    const int gr = m0 + row;
    const int xrow = ((gr >> 9) << 10) + (gr & 511) + a_off;
    const f32x4* pa = (const f32x4*)(X + (size_t)xrow * DDIM + slot * 8);
    const f32x4* pb = (const f32x4*)(Bm + (size_t)(n0 + row) * DDIM + slot * 8);
    short8 wa = cvt8(pa[0], pa[1]);
    short8 wb = cvt8(pb[0], pb[1]);
    const int ss = (slot ^ (row & 15)) * 8;
    *(short8*)&ldsA[row * 128 + ss] = wa;
    *(short8*)&ldsB[row * 128 + ss] = wb;
  }
  __syncthreads();
  const int lane = t & 63;
  const int wv = t >> 6;
  const int wr = wv >> 1, wc = wv & 1;
  const int la = lane & 31, lb = lane >> 5;
  short8 bfr[8][2];
  hoist_b(ldsB, bfr, wc, la, lb);
  f32x16 acc[2][2] = {};
  tile_mfma(ldsA, bfr, acc, wr, la, lb);
  store_acc(acc, C, ldc, m0, n0, wr, wc, la, lb);
}

__global__ void y_kernel(const int* __restrict__ y, float* __restrict__ out) {
  const int i = blockIdx.x * blockDim.x + threadIdx.x;
  if (i < BATCH * NPOS) out[i] = (float)y[i];
}

__global__ __launch_bounds__(256) void newmem_kernel(
    const float* __restrict__ X, const int* __restrict__ vis,
    const float* __restrict__ Mem, const int* __restrict__ lru_p,
    float* __restrict__ out) {
  const int r = blockIdx.x * 4 + (threadIdx.x >> 6);
  const int start = NPOS + lru_p[0] * (NNEG * BATCH);
  newmem_row(r, threadIdx.x & 63, X, vis, Mem, start, out);
}

extern "C" void kernel_launch(void* const* d_in, const int* in_sizes, int n_in,
                              void* d_out, int out_size, void* d_ws, size_t ws_size,
                              hipStream_t stream) {
  const float* x = (const float*)d_in[0];
  const int* y = (const int*)d_in[1];
  const int* visible = (const int*)d_in[2];
  const float* memory = (const float*)d_in[3];
  const int* lru = (const int*)d_in[4];
  float* out = (float*)d_out;

  const size_t OFF_Y = (size_t)BATCH * NPOS * NLEM;
  const size_t OFF_NOISE = OFF_Y + (size_t)BATCH * NPOS;
  const size_t OFF_MEM = OFF_NOISE + (size_t)BATCH * NNEG * NPOS;

  const size_t need = (size_t)(NX_ELEM + NM_ELEM) * 2;  // 10.5 MB bf16 scratch
  if (ws_size >= need) {
    unsigned short* xb = (unsigned short*)d_ws;
    unsigned short* mb = xb + NX_ELEM;
    prep_kernel<<<10768, 256, 0, stream>>>(
        x, y, visible, memory, lru, xb, mb, out + OFF_Y, out + OFF_MEM);
    gemm_band2_kernel<<<512, 256, 0, stream>>>(xb, mb, out, out + OFF_NOISE);
  } else {
    gemm_conv_kernel<<<dim3(32, 256), 256, 0, stream>>>(x, memory, out, NLEM, 0);
    gemm_conv_kernel<<<dim3(32, 4), 256, 0, stream>>>(x, memory, out + OFF_NOISE, NPOS, NPOS);
    y_kernel<<<16, 256, 0, stream>>>(y, out + OFF_Y);
    newmem_kernel<<<NLEM / 4, 256, 0, stream>>>(x, visible, memory, lru, out + OFF_MEM);
  }
}